// Round 1
// baseline (258.306 us; speedup 1.0000x reference)
//
#include <hip/hip_runtime.h>

#define D 128

// ---------------------------------------------------------------------------
// Kernel 0: segment start offsets from sorted node_idx.
// offs[n] = first pair p with node_idx[p] >= n ; offs[n_nodes] = n_pairs.
// ---------------------------------------------------------------------------
__global__ void seg_offsets_kernel(const int* __restrict__ node_idx,
                                   int* __restrict__ offs,
                                   int n_pairs, int n_nodes) {
    int p = blockIdx.x * blockDim.x + threadIdx.x;
    if (p >= n_pairs) return;
    int cur  = node_idx[p];
    int prev = (p == 0) ? -1 : node_idx[p - 1];
    // every node n with prev < n <= cur has its segment starting at p
    for (int n = prev + 1; n <= cur; ++n) offs[n] = p;
    if (p == n_pairs - 1) {
        for (int n = cur + 1; n <= n_nodes; ++n) offs[n] = n_pairs;
    }
}

// ---------------------------------------------------------------------------
// Kernel 1: per-node gather + weighted segment sum.
// 1 block of 128 threads per node. 4 groups of 32 lanes; group g handles
// pairs start+g, start+g+4, ... with float4 (16B/lane) gathers.
// ---------------------------------------------------------------------------
__global__ __launch_bounds__(128) void aggregate_kernel(
    const float* __restrict__ F, const float* __restrict__ pw,
    const int* __restrict__ pi, const int* __restrict__ pj,
    const int* __restrict__ offs, float* __restrict__ agg) {
    const int n     = blockIdx.x;
    const int start = offs[n];
    const int end   = offs[n + 1];
    const int lane  = threadIdx.x & 31;
    const int g     = threadIdx.x >> 5;

    float4 acc = make_float4(0.f, 0.f, 0.f, 0.f);
    for (int p = start + g; p < end; p += 4) {
        const int   i  = pi[p];
        const int   j  = pj[p];
        const float wv = pw[p];
        const float4 fi = *reinterpret_cast<const float4*>(F + (size_t)i * D + lane * 4);
        const float4 fj = *reinterpret_cast<const float4*>(F + (size_t)j * D + lane * 4);
        acc.x += (fi.x + fj.x) * wv;
        acc.y += (fi.y + fj.y) * wv;
        acc.z += (fi.z + fj.z) * wv;
        acc.w += (fi.w + fj.w) * wv;
    }

    __shared__ float red[4][D];
    *reinterpret_cast<float4*>(&red[g][lane * 4]) = acc;
    __syncthreads();

    const int d = threadIdx.x;  // 0..127
    const float s = red[0][d] + red[1][d] + red[2][d] + red[3][d];
    agg[(size_t)n * D + d] = s;
}

// ---------------------------------------------------------------------------
// Kernel 2: out = agg @ W + bias.  M x 128 @ 128 x 128.
// 256 threads/block, 64 rows/block. W (64KB) + A-rows (32KB) staged in LDS.
// Each thread: 8 rows x 4 cols register microtile.
// ---------------------------------------------------------------------------
__global__ __launch_bounds__(256) void proj_kernel(
    const float* __restrict__ agg, const float* __restrict__ W,
    const float* __restrict__ bias, float* __restrict__ out, int M) {
    __shared__ float Wl[D * D];    // 64 KB
    __shared__ float Al[64 * D];   // 32 KB
    const int tid = threadIdx.x;

    // stage W: 4096 float4 / 256 threads = 16 each
    for (int t = tid; t < D * D / 4; t += 256)
        reinterpret_cast<float4*>(Wl)[t] = reinterpret_cast<const float4*>(W)[t];

    const int row0 = blockIdx.x * 64;
    // stage 64 rows of agg: 2048 float4 / 256 threads = 8 each
    for (int t = tid; t < 64 * D / 4; t += 256) {
        const int r = row0 + (t >> 5);  // 32 float4 per row
        float4 v = make_float4(0.f, 0.f, 0.f, 0.f);
        if (r < M) v = reinterpret_cast<const float4*>(agg)[(size_t)row0 * (D / 4) + t];
        reinterpret_cast<float4*>(Al)[t] = v;
    }
    __syncthreads();

    const int tcol = tid & 31;   // 32 column-groups of 4
    const int trow = tid >> 5;   // 8 row-groups of 8
    float acc[8][4];
#pragma unroll
    for (int r = 0; r < 8; ++r)
#pragma unroll
        for (int c = 0; c < 4; ++c) acc[r][c] = 0.f;

    for (int d = 0; d < D; ++d) {
        const float4 wv = *reinterpret_cast<const float4*>(&Wl[d * D + tcol * 4]);
#pragma unroll
        for (int r = 0; r < 8; ++r) {
            const float a = Al[(trow * 8 + r) * D + d];
            acc[r][0] += a * wv.x;
            acc[r][1] += a * wv.y;
            acc[r][2] += a * wv.z;
            acc[r][3] += a * wv.w;
        }
    }

    const float4 bv = *reinterpret_cast<const float4*>(&bias[tcol * 4]);
#pragma unroll
    for (int r = 0; r < 8; ++r) {
        const int row = row0 + trow * 8 + r;
        if (row < M) {
            float4 o;
            o.x = acc[r][0] + bv.x;
            o.y = acc[r][1] + bv.y;
            o.z = acc[r][2] + bv.z;
            o.w = acc[r][3] + bv.w;
            *reinterpret_cast<float4*>(&out[(size_t)row * D + tcol * 4]) = o;
        }
    }
}

// ---------------------------------------------------------------------------
extern "C" void kernel_launch(void* const* d_in, const int* in_sizes, int n_in,
                              void* d_out, int out_size, void* d_ws, size_t ws_size,
                              hipStream_t stream) {
    const float* F    = (const float*)d_in[0];   // [n_nodes,128]
    const float* pw   = (const float*)d_in[1];   // [n_pairs]
    const float* W    = (const float*)d_in[2];   // [128,128]
    const float* bias = (const float*)d_in[3];   // [128]
    const int*   pi   = (const int*)d_in[4];
    const int*   pj   = (const int*)d_in[5];
    const int*   nidx = (const int*)d_in[6];
    float* out = (float*)d_out;

    const int n_pairs = in_sizes[1];
    const int n_nodes = in_sizes[0] / D;

    float* agg = (float*)d_ws;                                    // n_nodes*128 f32 = 25.6 MB
    int*   offs = (int*)((char*)d_ws + (size_t)n_nodes * D * 4);  // n_nodes+1 ints

    seg_offsets_kernel<<<(n_pairs + 255) / 256, 256, 0, stream>>>(nidx, offs, n_pairs, n_nodes);
    aggregate_kernel<<<n_nodes, 128, 0, stream>>>(F, pw, pi, pj, offs, agg);
    proj_kernel<<<(n_nodes + 63) / 64, 256, 0, stream>>>(agg, W, bias, out, n_nodes);
}

// Round 2
// 159.494 us; speedup vs baseline: 1.6195x; 1.6195x over previous
//
#include <hip/hip_runtime.h>

#define D 128

__device__ __forceinline__ float bf_lo(unsigned u) { return __uint_as_float(u << 16); }
__device__ __forceinline__ float bf_hi(unsigned u) { return __uint_as_float(u & 0xffff0000u); }

// ---------------------------------------------------------------------------
// Kernel A: convert features f32 -> packed bf16 (RNE). 4 floats -> 1 uint2.
// ---------------------------------------------------------------------------
__global__ __launch_bounds__(256) void cvt_bf16_kernel(const float* __restrict__ F,
                                                       unsigned* __restrict__ Fb,
                                                       int n4) {
    int t = blockIdx.x * blockDim.x + threadIdx.x;
    if (t >= n4) return;
    float4 v = reinterpret_cast<const float4*>(F)[t];
    unsigned b[4];
    b[0] = __float_as_uint(v.x); b[1] = __float_as_uint(v.y);
    b[2] = __float_as_uint(v.z); b[3] = __float_as_uint(v.w);
#pragma unroll
    for (int k = 0; k < 4; ++k)  // round-to-nearest-even to bf16
        b[k] = (b[k] + 0x7fffu + ((b[k] >> 16) & 1u)) >> 16;
    uint2 o;
    o.x = b[0] | (b[1] << 16);
    o.y = b[2] | (b[3] << 16);
    reinterpret_cast<uint2*>(Fb)[t] = o;
}

// ---------------------------------------------------------------------------
// Kernel 0: segment start offsets from sorted node_idx.
// ---------------------------------------------------------------------------
__global__ void seg_offsets_kernel(const int* __restrict__ node_idx,
                                   int* __restrict__ offs,
                                   int n_pairs, int n_nodes) {
    int p = blockIdx.x * blockDim.x + threadIdx.x;
    if (p >= n_pairs) return;
    int cur  = node_idx[p];
    int prev = (p == 0) ? -1 : node_idx[p - 1];
    for (int n = prev + 1; n <= cur; ++n) offs[n] = p;
    if (p == n_pairs - 1) {
        for (int n = cur + 1; n <= n_nodes; ++n) offs[n] = n_pairs;
    }
}

// ---------------------------------------------------------------------------
// Kernel 1: per-node gather (bf16 rows) + weighted segment sum (f32 acc).
// 128 threads/block = 8 groups x 16 lanes. Lane loads uint4 = 8 bf16 = 16B;
// 16 lanes x 16B = one 256B row. Group g takes pairs start+g, start+g+8, ...
// ---------------------------------------------------------------------------
__global__ __launch_bounds__(128) void aggregate_kernel(
    const unsigned* __restrict__ Fb,  // [n_nodes][D/2] packed bf16
    const float* __restrict__ pw,
    const int* __restrict__ pi, const int* __restrict__ pj,
    const int* __restrict__ offs, float* __restrict__ agg) {
    const int n     = blockIdx.x;
    const int start = offs[n];
    const int end   = offs[n + 1];
    const int lane  = threadIdx.x & 15;
    const int g     = threadIdx.x >> 4;

    float acc[8];
#pragma unroll
    for (int k = 0; k < 8; ++k) acc[k] = 0.f;

    for (int p = start + g; p < end; p += 8) {
        const int   i  = pi[p];
        const int   j  = pj[p];
        const float wv = pw[p];
        const uint4 ui = *reinterpret_cast<const uint4*>(Fb + (size_t)i * (D / 2) + lane * 4);
        const uint4 uj = *reinterpret_cast<const uint4*>(Fb + (size_t)j * (D / 2) + lane * 4);
        acc[0] += (bf_lo(ui.x) + bf_lo(uj.x)) * wv;
        acc[1] += (bf_hi(ui.x) + bf_hi(uj.x)) * wv;
        acc[2] += (bf_lo(ui.y) + bf_lo(uj.y)) * wv;
        acc[3] += (bf_hi(ui.y) + bf_hi(uj.y)) * wv;
        acc[4] += (bf_lo(ui.z) + bf_lo(uj.z)) * wv;
        acc[5] += (bf_hi(ui.z) + bf_hi(uj.z)) * wv;
        acc[6] += (bf_lo(ui.w) + bf_lo(uj.w)) * wv;
        acc[7] += (bf_hi(ui.w) + bf_hi(uj.w)) * wv;
    }

    __shared__ float red[8][D];
#pragma unroll
    for (int k = 0; k < 8; ++k) red[g][lane * 8 + k] = acc[k];
    __syncthreads();

    const int d = threadIdx.x;  // 0..127
    float s = 0.f;
#pragma unroll
    for (int q = 0; q < 8; ++q) s += red[q][d];
    agg[(size_t)n * D + d] = s;
}

// ---------------------------------------------------------------------------
// Kernel 2: out = agg @ W + bias.  M x 128 @ 128 x 128. (unchanged)
// ---------------------------------------------------------------------------
__global__ __launch_bounds__(256) void proj_kernel(
    const float* __restrict__ agg, const float* __restrict__ W,
    const float* __restrict__ bias, float* __restrict__ out, int M) {
    __shared__ float Wl[D * D];    // 64 KB
    __shared__ float Al[64 * D];   // 32 KB
    const int tid = threadIdx.x;

    for (int t = tid; t < D * D / 4; t += 256)
        reinterpret_cast<float4*>(Wl)[t] = reinterpret_cast<const float4*>(W)[t];

    const int row0 = blockIdx.x * 64;
    for (int t = tid; t < 64 * D / 4; t += 256) {
        const int r = row0 + (t >> 5);
        float4 v = make_float4(0.f, 0.f, 0.f, 0.f);
        if (r < M) v = reinterpret_cast<const float4*>(agg)[(size_t)row0 * (D / 4) + t];
        reinterpret_cast<float4*>(Al)[t] = v;
    }
    __syncthreads();

    const int tcol = tid & 31;
    const int trow = tid >> 5;
    float acc[8][4];
#pragma unroll
    for (int r = 0; r < 8; ++r)
#pragma unroll
        for (int c = 0; c < 4; ++c) acc[r][c] = 0.f;

    for (int d = 0; d < D; ++d) {
        const float4 wv = *reinterpret_cast<const float4*>(&Wl[d * D + tcol * 4]);
#pragma unroll
        for (int r = 0; r < 8; ++r) {
            const float a = Al[(trow * 8 + r) * D + d];
            acc[r][0] += a * wv.x;
            acc[r][1] += a * wv.y;
            acc[r][2] += a * wv.z;
            acc[r][3] += a * wv.w;
        }
    }

    const float4 bv = *reinterpret_cast<const float4*>(&bias[tcol * 4]);
#pragma unroll
    for (int r = 0; r < 8; ++r) {
        const int row = row0 + trow * 8 + r;
        if (row < M) {
            float4 o;
            o.x = acc[r][0] + bv.x;
            o.y = acc[r][1] + bv.y;
            o.z = acc[r][2] + bv.z;
            o.w = acc[r][3] + bv.w;
            *reinterpret_cast<float4*>(&out[(size_t)row * D + tcol * 4]) = o;
        }
    }
}

// ---------------------------------------------------------------------------
extern "C" void kernel_launch(void* const* d_in, const int* in_sizes, int n_in,
                              void* d_out, int out_size, void* d_ws, size_t ws_size,
                              hipStream_t stream) {
    const float* F    = (const float*)d_in[0];
    const float* pw   = (const float*)d_in[1];
    const float* W    = (const float*)d_in[2];
    const float* bias = (const float*)d_in[3];
    const int*   pi   = (const int*)d_in[4];
    const int*   pj   = (const int*)d_in[5];
    const int*   nidx = (const int*)d_in[6];
    float* out = (float*)d_out;

    const int n_pairs = in_sizes[1];
    const int n_nodes = in_sizes[0] / D;

    const size_t agg_bytes  = (size_t)n_nodes * D * 4;
    const size_t offs_bytes = (size_t)(n_nodes + 1) * 4;
    const size_t fb_bytes   = (size_t)n_nodes * D * 2;

    float*    agg  = (float*)d_ws;
    int*      offs = (int*)((char*)d_ws + agg_bytes);
    // Fb: in ws if it fits, else use d_out as scratch (proj overwrites it last,
    // and proj does not read Fb).
    unsigned* Fb;
    size_t used = agg_bytes + ((offs_bytes + 255) & ~(size_t)255);
    if (ws_size >= used + fb_bytes) {
        Fb = (unsigned*)((char*)d_ws + used);
    } else {
        Fb = (unsigned*)d_out;
    }

    const int n4 = n_nodes * D / 4;
    cvt_bf16_kernel<<<(n4 + 255) / 256, 256, 0, stream>>>(F, Fb, n4);
    seg_offsets_kernel<<<(n_pairs + 255) / 256, 256, 0, stream>>>(nidx, offs, n_pairs, n_nodes);
    aggregate_kernel<<<n_nodes, 128, 0, stream>>>(Fb, pw, pi, pj, offs, agg);
    proj_kernel<<<(n_nodes + 63) / 64, 256, 0, stream>>>(agg, W, bias, out, n_nodes);
}